// Round 3
// baseline (1061.358 us; speedup 1.0000x reference)
//
#include <hip/hip_runtime.h>
#include <stdint.h>

#define ROWS 65536          // B * H * W tokens
#define NWT  1024           // total windows (16 * 64)
#define SCALE 0.17677669529663687f

typedef unsigned short u16;
typedef __attribute__((ext_vector_type(8))) short bf16x8;
typedef __attribute__((ext_vector_type(4))) float f32x4;
typedef __attribute__((ext_vector_type(8))) unsigned short u16x8;
typedef __attribute__((ext_vector_type(4))) unsigned short u16x4;

__device__ __forceinline__ float bf2f(u16 u){
  union { unsigned int i; float f; } c; c.i = ((unsigned int)u) << 16; return c.f;
}
__device__ __forceinline__ u16 f2bf(float f){
  union { float f; unsigned int i; } c; c.f = f;
  unsigned int r = c.i + 0x7fffu + ((c.i >> 16) & 1u);
  return (u16)(r >> 16);
}
__device__ __forceinline__ int regid(int a){ return a < 56 ? 0 : (a < 60 ? 1 : 2); }

// ---------------- fp32 residual copy ----------------
__global__ __launch_bounds__(256) void cvt_copy(const float* __restrict__ in, float* __restrict__ out){
  int i = (blockIdx.x * 256 + threadIdx.x) * 8;
  float4 a = *(const float4*)&in[i];
  float4 b = *(const float4*)&in[i + 4];
  *(float4*)&out[i]     = a;
  *(float4*)&out[i + 4] = b;
}

// ---------------- all weight transposes (K,N)fp32 -> (N,K)bf16 ----------------
__global__ __launch_bounds__(256) void transpose_all(
    const float* s0, const float* s1, const float* s2, const float* s3,
    const float* s4, const float* s5, const float* s6, const float* s7, u16* wt)
{
  __shared__ __align__(16) u16 t[32][33];
  const float* src; int K, N; size_t doff;
  switch (blockIdx.z){
    case 0: src = s0; K = 256;  N = 768;  doff = 0;               break;
    case 1: src = s1; K = 256;  N = 256;  doff = 196608;          break;
    case 2: src = s2; K = 256;  N = 1024; doff = 262144;          break;
    case 3: src = s3; K = 1024; N = 256;  doff = 524288;          break;
    case 4: src = s4; K = 256;  N = 768;  doff = 786432 + 0;      break;
    case 5: src = s5; K = 256;  N = 256;  doff = 786432 + 196608; break;
    case 6: src = s6; K = 256;  N = 1024; doff = 786432 + 262144; break;
    default:src = s7; K = 1024; N = 256;  doff = 786432 + 524288; break;
  }
  int n0 = blockIdx.x * 32, k0 = blockIdx.y * 32;
  if (n0 >= N || k0 >= K) return;
  int tx = threadIdx.x & 31, ty = threadIdx.x >> 5;
  #pragma unroll
  for (int i = 0; i < 32; i += 8) t[ty + i][tx] = f2bf(src[(size_t)(k0 + ty + i) * N + n0 + tx]);
  __syncthreads();
  u16* dst = wt + doff;
  #pragma unroll
  for (int i = 0; i < 32; i += 8) dst[(size_t)(n0 + ty + i) * K + k0 + tx] = t[tx][ty + i];
}

// ---------------- LayerNorm (optionally fused shift + window partition) ----------------
// one wave per output row; out is bf16 (ROWS,256)
__global__ __launch_bounds__(256) void ln_kernel(
    const float* __restrict__ X, const float* __restrict__ g, const float* __restrict__ bt,
    u16* __restrict__ out, int windowed, int shift)
{
  int wv = (blockIdx.x * 256 + threadIdx.x) >> 6;  // output row
  int lane = threadIdx.x & 63;
  int srow;
  if (windowed){
    int win = wv >> 6, n = wv & 63;
    int b = win >> 6, wh = (win >> 3) & 7, ww = win & 7;
    int h = (wh * 8 + (n >> 3) + shift) & 63;
    int w = (ww * 8 + (n & 7) + shift) & 63;
    srow = (b << 12) + h * 64 + w;
  } else srow = wv;
  const float* xr = X + (size_t)srow * 256;
  float4 v = *(const float4*)&xr[lane * 4];
  float s  = v.x + v.y + v.z + v.w;
  float s2 = v.x * v.x + v.y * v.y + v.z * v.z + v.w * v.w;
  #pragma unroll
  for (int m = 32; m; m >>= 1){ s += __shfl_xor(s, m); s2 += __shfl_xor(s2, m); }
  float mu = s * (1.f / 256.f);
  float var = s2 * (1.f / 256.f) - mu * mu;
  float rstd = rsqrtf(var + 1e-5f);
  float4 gu = *(const float4*)&g[lane * 4];
  float4 bu = *(const float4*)&bt[lane * 4];
  u16x4 o;
  o[0] = f2bf((v.x - mu) * rstd * gu.x + bu.x);
  o[1] = f2bf((v.y - mu) * rstd * gu.y + bu.y);
  o[2] = f2bf((v.z - mu) * rstd * gu.z + bu.z);
  o[3] = f2bf((v.w - mu) * rstd * gu.w + bu.w);
  *(u16x4*)&out[(size_t)wv * 256 + lane * 4] = o;
}

// ---------------- bf16 MFMA GEMM, A (M,K) x Bt (N,K), 128x128 tile ----------------
// EPI: 0 = bias->bf16 (qkv)   1 = bias + window-reverse/roll scatter-add into X (proj)
//      2 = bias + exact GELU -> bf16 (fc1)
//      3 = bias + X += val (fc2 blk0)   4 = bias + outf_fp32 = X + val (fc2 blk1, final)
template<int EPI>
__global__ __launch_bounds__(256) void gemm_bt(
    const u16* __restrict__ A, const u16* __restrict__ Bt, const float* __restrict__ bias,
    u16* __restrict__ outb, float* __restrict__ outf, float* __restrict__ X,
    int N, int K, int shift)
{
  __shared__ __align__(16) u16 As[128 * 64];
  __shared__ __align__(16) u16 Bs[128 * 64];
  int tid = threadIdx.x;
  int lane = tid & 63, wave = tid >> 6;
  int m0 = blockIdx.y * 128, n0 = blockIdx.x * 128;
  int wm = (wave >> 1) * 64, wn = (wave & 1) * 64;
  f32x4 acc[4][4];
  #pragma unroll
  for (int i = 0; i < 4; i++)
    #pragma unroll
    for (int j = 0; j < 4; j++)
      #pragma unroll
      for (int r = 0; r < 4; r++) acc[i][j][r] = 0.f;

  int lrow = tid >> 3, lcol = (tid & 7) * 8;
  const u16* Ag = A + (size_t)(m0 + lrow) * K + lcol;
  const u16* Bg = Bt + (size_t)(n0 + lrow) * K + lcol;
  u16* Asd = &As[lrow * 64 + lcol];
  u16* Bsd = &Bs[lrow * 64 + lcol];
  int r = lane & 15, koff = (lane >> 4) * 8;

  for (int kt = 0; kt < K; kt += 64){
    u16x8 ta[4], tb[4];
    #pragma unroll
    for (int i = 0; i < 4; i++) ta[i] = *(const u16x8*)(Ag + (size_t)i * 32 * K + kt);
    #pragma unroll
    for (int i = 0; i < 4; i++) tb[i] = *(const u16x8*)(Bg + (size_t)i * 32 * K + kt);
    #pragma unroll
    for (int i = 0; i < 4; i++) *(u16x8*)(Asd + i * 32 * 64) = ta[i];
    #pragma unroll
    for (int i = 0; i < 4; i++) *(u16x8*)(Bsd + i * 32 * 64) = tb[i];
    __syncthreads();
    #pragma unroll
    for (int kk = 0; kk < 64; kk += 32){
      bf16x8 af[4], bfr[4];
      #pragma unroll
      for (int i = 0; i < 4; i++) af[i]  = *(const bf16x8*)&As[(wm + i * 16 + r) * 64 + kk + koff];
      #pragma unroll
      for (int j = 0; j < 4; j++) bfr[j] = *(const bf16x8*)&Bs[(wn + j * 16 + r) * 64 + kk + koff];
      #pragma unroll
      for (int i = 0; i < 4; i++)
        #pragma unroll
        for (int j = 0; j < 4; j++)
          acc[i][j] = __builtin_amdgcn_mfma_f32_16x16x32_bf16(af[i], bfr[j], acc[i][j], 0, 0, 0);
    }
    __syncthreads();
  }

  int cq = lane >> 4, cr = lane & 15;
  #pragma unroll
  for (int j = 0; j < 4; j++){
    int col = n0 + wn + j * 16 + cr;
    float bv = bias[col];
    #pragma unroll
    for (int i = 0; i < 4; i++){
      #pragma unroll
      for (int rr = 0; rr < 4; rr++){
        int row = m0 + wm + i * 16 + cq * 4 + rr;
        float val = acc[i][j][rr] + bv;
        if (EPI == 0){
          outb[(size_t)row * N + col] = f2bf(val);
        } else if (EPI == 2){
          float gg = 0.5f * val * (1.f + erff(val * 0.70710678118f));
          outb[(size_t)row * N + col] = f2bf(gg);
        } else if (EPI == 1){
          int win = row >> 6, n = row & 63;
          int b = win >> 6, wh = (win >> 3) & 7, ww = win & 7;
          int h = (wh * 8 + (n >> 3) + shift) & 63;
          int w = (ww * 8 + (n & 7) + shift) & 63;
          X[((size_t)(b << 12) + h * 64 + w) * 256 + col] += val;
        } else if (EPI == 3){
          X[(size_t)row * 256 + col] += val;
        } else {
          outf[(size_t)row * 256 + col] = X[(size_t)row * 256 + col] + val;
        }
      }
    }
  }
}

// ---------------- window attention: one block per window, wave h = head h ----------------
__global__ __launch_bounds__(512) void attn_kernel(
    const u16* __restrict__ qkv, const float* __restrict__ rpb,
    u16* __restrict__ out, int shifted)
{
  __shared__ __align__(16) u16 kv_s[64 * 256];   // K phase then V phase (32 KB)
  __shared__ float rpb_s[225 * 8];
  int win = blockIdx.x;
  int head = threadIdx.x >> 6;
  int lane = threadIdx.x & 63;          // query token n

  for (int i = threadIdx.x; i < 1800; i += 512) rpb_s[i] = rpb[i];
  const u16* base = qkv + (size_t)win * 64 * 768;
  for (int ch = threadIdx.x; ch < 2048; ch += 512){
    int m = ch >> 5, c = (ch & 31) * 8;
    *(u16x8*)&kv_s[m * 256 + c] = *(const u16x8*)&base[m * 768 + 256 + c];
  }
  float q[32];
  {
    const u16* qp = base + lane * 768 + head * 32;
    #pragma unroll
    for (int d8 = 0; d8 < 32; d8 += 8){
      u16x8 u = *(const u16x8*)&qp[d8];
      #pragma unroll
      for (int jj = 0; jj < 8; jj++) q[d8 + jj] = bf2f(u[jj]) * SCALE;
    }
  }
  __syncthreads();

  int nh = lane >> 3, nw = lane & 7;
  int wh = (win >> 3) & 7, ww = win & 7;
  int idn = 0;
  if (shifted) idn = 3 * regid(wh * 8 + nh) + regid(ww * 8 + nw);

  float s[64];
  float mx = -1e30f;
  #pragma unroll
  for (int m = 0; m < 64; m++){
    float a = 0.f;
    const u16* kp = &kv_s[m * 256 + head * 32];
    #pragma unroll
    for (int d8 = 0; d8 < 32; d8 += 8){
      u16x8 u = *(const u16x8*)&kp[d8];
      #pragma unroll
      for (int jj = 0; jj < 8; jj++) a += q[d8 + jj] * bf2f(u[jj]);
    }
    int mh = m >> 3, mw = m & 7;
    a += rpb_s[((nh - mh + 7) * 15 + (nw - mw + 7)) * 8 + head];
    if (shifted){
      int idm = 3 * regid(wh * 8 + mh) + regid(ww * 8 + mw);
      if (idm != idn) a -= 100.f;
    }
    s[m] = a;
    mx = fmaxf(mx, a);
  }
  float sum = 0.f;
  #pragma unroll
  for (int m = 0; m < 64; m++){ float e = __expf(s[m] - mx); s[m] = e; sum += e; }
  float inv = 1.f / sum;

  __syncthreads();   // everyone done with K
  for (int ch = threadIdx.x; ch < 2048; ch += 512){
    int m = ch >> 5, c = (ch & 31) * 8;
    *(u16x8*)&kv_s[m * 256 + c] = *(const u16x8*)&base[m * 768 + 512 + c];
  }
  __syncthreads();

  float o[32];
  #pragma unroll
  for (int d = 0; d < 32; d++) o[d] = 0.f;
  #pragma unroll
  for (int m = 0; m < 64; m++){
    float pm = s[m];
    const u16* vp = &kv_s[m * 256 + head * 32];
    #pragma unroll
    for (int d8 = 0; d8 < 32; d8 += 8){
      u16x8 u = *(const u16x8*)&vp[d8];
      #pragma unroll
      for (int jj = 0; jj < 8; jj++) o[d8 + jj] += pm * bf2f(u[jj]);
    }
  }
  u16* op = out + (size_t)(win * 64 + lane) * 256 + head * 32;
  #pragma unroll
  for (int d8 = 0; d8 < 32; d8 += 8){
    u16x8 u;
    #pragma unroll
    for (int jj = 0; jj < 8; jj++) u[jj] = f2bf(o[d8 + jj] * inv);
    *(u16x8*)&op[d8] = u;
  }
}

// ---------------- launch ----------------
extern "C" void kernel_launch(void* const* d_in, const int* in_sizes, int n_in,
                              void* d_out, int out_size, void* d_ws, size_t ws_size,
                              hipStream_t stream)
{
  const float* x = (const float*)d_in[0];
  const float* p[2][13];
  for (int blk = 0; blk < 2; blk++)
    for (int i = 0; i < 13; i++) p[blk][i] = (const float*)d_in[1 + blk * 13 + i];
  // 0 n1g 1 n1b 2 qkvw 3 qkvb 4 rpb 5 pw 6 pb 7 n2g 8 n2b 9 f1w 10 f1b 11 f2w 12 f2b

  char* ws = (char*)d_ws;
  float* X  = (float*)ws;                            // 64 MB fp32 residual
  u16* HW   = (u16*)(ws + ((size_t)64 << 20));       // 32 MB (LN out / attn out)
  u16* BIG  = (u16*)(ws + ((size_t)96 << 20));       // 128 MB (QKV / MLP hidden)
  u16* WT   = (u16*)(ws + ((size_t)224 << 20));      // 3 MB transposed bf16 weights

  cvt_copy<<<ROWS * 256 / (256 * 8), 256, 0, stream>>>(x, X);
  transpose_all<<<dim3(32, 32, 8), 256, 0, stream>>>(
      p[0][2], p[0][5], p[0][9], p[0][11], p[1][2], p[1][5], p[1][9], p[1][11], WT);

  for (int blk = 0; blk < 2; blk++){
    int shift = blk ? 4 : 0;
    const u16* qkvw_t = WT + (size_t)blk * 786432;
    const u16* pw_t   = WT + (size_t)blk * 786432 + 196608;
    const u16* f1w_t  = WT + (size_t)blk * 786432 + 262144;
    const u16* f2w_t  = WT + (size_t)blk * 786432 + 524288;

    ln_kernel<<<ROWS / 4, 256, 0, stream>>>(X, p[blk][0], p[blk][1], HW, 1, shift);
    gemm_bt<0><<<dim3(6, 512), 256, 0, stream>>>(HW, qkvw_t, p[blk][3], BIG, nullptr, X, 768, 256, 0);
    attn_kernel<<<NWT, 512, 0, stream>>>(BIG, p[blk][4], HW, blk);
    gemm_bt<1><<<dim3(2, 512), 256, 0, stream>>>(HW, pw_t, p[blk][6], nullptr, nullptr, X, 256, 256, shift);
    ln_kernel<<<ROWS / 4, 256, 0, stream>>>(X, p[blk][7], p[blk][8], HW, 0, 0);
    gemm_bt<2><<<dim3(8, 512), 256, 0, stream>>>(HW, f1w_t, p[blk][10], BIG, nullptr, X, 1024, 256, 0);
    if (blk == 0)
      gemm_bt<3><<<dim3(2, 512), 256, 0, stream>>>(BIG, f2w_t, p[blk][12], nullptr, nullptr, X, 256, 1024, 0);
    else
      gemm_bt<4><<<dim3(2, 512), 256, 0, stream>>>(BIG, f2w_t, p[blk][12], nullptr, (float*)d_out, X, 256, 1024, 0);
  }
}

// Round 4
// 856.514 us; speedup vs baseline: 1.2392x; 1.2392x over previous
//
#include <hip/hip_runtime.h>
#include <stdint.h>

#define ROWS 65536          // B * H * W tokens
#define NWT  1024           // total windows (16 * 64)
#define SCALE 0.17677669529663687f

typedef unsigned short u16;
typedef __attribute__((ext_vector_type(8))) short bf16x8;
typedef __attribute__((ext_vector_type(4))) float f32x4;
typedef __attribute__((ext_vector_type(8))) unsigned short u16x8;
typedef __attribute__((ext_vector_type(4))) unsigned short u16x4;

__device__ __forceinline__ float bf2f(u16 u){
  union { unsigned int i; float f; } c; c.i = ((unsigned int)u) << 16; return c.f;
}
__device__ __forceinline__ u16 f2bf(float f){
  union { float f; unsigned int i; } c; c.f = f;
  unsigned int r = c.i + 0x7fffu + ((c.i >> 16) & 1u);
  return (u16)(r >> 16);
}
__device__ __forceinline__ void async_copy16(const u16* g, u16* l){
  __builtin_amdgcn_global_load_lds((const __attribute__((address_space(1))) unsigned int*)g,
                                   (__attribute__((address_space(3))) unsigned int*)l, 16, 0, 0);
}
__device__ __forceinline__ int regid(int a){ return a < 56 ? 0 : (a < 60 ? 1 : 2); }

// ---------------- fp32 residual copy ----------------
__global__ __launch_bounds__(256) void cvt_copy(const float* __restrict__ in, float* __restrict__ out){
  int i = (blockIdx.x * 256 + threadIdx.x) * 8;
  float4 a = *(const float4*)&in[i];
  float4 b = *(const float4*)&in[i + 4];
  *(float4*)&out[i]     = a;
  *(float4*)&out[i + 4] = b;
}

// ---------------- all weight transposes (K,N)fp32 -> (N,K)bf16 ----------------
__global__ __launch_bounds__(256) void transpose_all(
    const float* s0, const float* s1, const float* s2, const float* s3,
    const float* s4, const float* s5, const float* s6, const float* s7, u16* wt)
{
  __shared__ __align__(16) u16 t[32][33];
  const float* src; int K, N; size_t doff;
  switch (blockIdx.z){
    case 0: src = s0; K = 256;  N = 768;  doff = 0;               break;
    case 1: src = s1; K = 256;  N = 256;  doff = 196608;          break;
    case 2: src = s2; K = 256;  N = 1024; doff = 262144;          break;
    case 3: src = s3; K = 1024; N = 256;  doff = 524288;          break;
    case 4: src = s4; K = 256;  N = 768;  doff = 786432 + 0;      break;
    case 5: src = s5; K = 256;  N = 256;  doff = 786432 + 196608; break;
    case 6: src = s6; K = 256;  N = 1024; doff = 786432 + 262144; break;
    default:src = s7; K = 1024; N = 256;  doff = 786432 + 524288; break;
  }
  int n0 = blockIdx.x * 32, k0 = blockIdx.y * 32;
  if (n0 >= N || k0 >= K) return;
  int tx = threadIdx.x & 31, ty = threadIdx.x >> 5;
  #pragma unroll
  for (int i = 0; i < 32; i += 8) t[ty + i][tx] = f2bf(src[(size_t)(k0 + ty + i) * N + n0 + tx]);
  __syncthreads();
  u16* dst = wt + doff;
  #pragma unroll
  for (int i = 0; i < 32; i += 8) dst[(size_t)(n0 + ty + i) * K + k0 + tx] = t[tx][ty + i];
}

// ---------------- LayerNorm (optionally fused shift + window partition) ----------------
__global__ __launch_bounds__(256) void ln_kernel(
    const float* __restrict__ X, const float* __restrict__ g, const float* __restrict__ bt,
    u16* __restrict__ out, int windowed, int shift)
{
  int wv = (blockIdx.x * 256 + threadIdx.x) >> 6;  // output row
  int lane = threadIdx.x & 63;
  int srow;
  if (windowed){
    int win = wv >> 6, n = wv & 63;
    int b = win >> 6, wh = (win >> 3) & 7, ww = win & 7;
    int h = (wh * 8 + (n >> 3) + shift) & 63;
    int w = (ww * 8 + (n & 7) + shift) & 63;
    srow = (b << 12) + h * 64 + w;
  } else srow = wv;
  const float* xr = X + (size_t)srow * 256;
  float4 v = *(const float4*)&xr[lane * 4];
  float s  = v.x + v.y + v.z + v.w;
  float s2 = v.x * v.x + v.y * v.y + v.z * v.z + v.w * v.w;
  #pragma unroll
  for (int m = 32; m; m >>= 1){ s += __shfl_xor(s, m); s2 += __shfl_xor(s2, m); }
  float mu = s * (1.f / 256.f);
  float var = s2 * (1.f / 256.f) - mu * mu;
  float rstd = rsqrtf(var + 1e-5f);
  float4 gu = *(const float4*)&g[lane * 4];
  float4 bu = *(const float4*)&bt[lane * 4];
  u16x4 o;
  o[0] = f2bf((v.x - mu) * rstd * gu.x + bu.x);
  o[1] = f2bf((v.y - mu) * rstd * gu.y + bu.y);
  o[2] = f2bf((v.z - mu) * rstd * gu.z + bu.z);
  o[3] = f2bf((v.w - mu) * rstd * gu.w + bu.w);
  *(u16x4*)&out[(size_t)wv * 256 + lane * 4] = o;
}

// ---------------- bf16 MFMA GEMM, A (M,K) x Bt (N,K), 128x128 tile ----------------
// EPI: 0 = bias->bf16 (qkv)   1 = bias + window-reverse/roll scatter-add into X (proj)
//      2 = bias + exact GELU -> bf16 (fc1)
//      3 = bias + X += val (fc2 blk0)   4 = bias + outf_fp32 = X + val (fc2 blk1, final)
template<int EPI>
__global__ __launch_bounds__(256) void gemm_bt(
    const u16* __restrict__ A, const u16* __restrict__ Bt, const float* __restrict__ bias,
    u16* __restrict__ outb, float* __restrict__ outf, float* __restrict__ X,
    int N, int K, int shift)
{
  __shared__ __align__(16) u16 As[128 * 64];
  __shared__ __align__(16) u16 Bs[128 * 64];
  int tid = threadIdx.x;
  int lane = tid & 63, wave = tid >> 6;
  int m0 = blockIdx.y * 128, n0 = blockIdx.x * 128;
  int wm = (wave >> 1) * 64, wn = (wave & 1) * 64;
  f32x4 acc[4][4];
  #pragma unroll
  for (int i = 0; i < 4; i++)
    #pragma unroll
    for (int j = 0; j < 4; j++)
      #pragma unroll
      for (int r = 0; r < 4; r++) acc[i][j][r] = 0.f;

  int lrow = tid >> 3, lcol = (tid & 7) * 8;
  const u16* Ag = A + (size_t)(m0 + lrow) * K + lcol;
  const u16* Bg = Bt + (size_t)(n0 + lrow) * K + lcol;
  u16* Asd = &As[lrow * 64 + lcol];
  u16* Bsd = &Bs[lrow * 64 + lcol];
  int r = lane & 15, koff = (lane >> 4) * 8;

  for (int kt = 0; kt < K; kt += 64){
    #pragma unroll
    for (int i = 0; i < 4; i++) async_copy16(Ag + (size_t)i * 32 * K + kt, Asd + i * 32 * 64);
    #pragma unroll
    for (int i = 0; i < 4; i++) async_copy16(Bg + (size_t)i * 32 * K + kt, Bsd + i * 32 * 64);
    __syncthreads();
    #pragma unroll
    for (int kk = 0; kk < 64; kk += 32){
      bf16x8 af[4], bfr[4];
      #pragma unroll
      for (int i = 0; i < 4; i++) af[i]  = *(const bf16x8*)&As[(wm + i * 16 + r) * 64 + kk + koff];
      #pragma unroll
      for (int j = 0; j < 4; j++) bfr[j] = *(const bf16x8*)&Bs[(wn + j * 16 + r) * 64 + kk + koff];
      #pragma unroll
      for (int i = 0; i < 4; i++)
        #pragma unroll
        for (int j = 0; j < 4; j++)
          acc[i][j] = __builtin_amdgcn_mfma_f32_16x16x32_bf16(af[i], bfr[j], acc[i][j], 0, 0, 0);
    }
    __syncthreads();
  }

  int cq = lane >> 4, cr = lane & 15;
  #pragma unroll
  for (int j = 0; j < 4; j++){
    int col = n0 + wn + j * 16 + cr;
    float bv = bias[col];
    #pragma unroll
    for (int i = 0; i < 4; i++){
      #pragma unroll
      for (int rr = 0; rr < 4; rr++){
        int row = m0 + wm + i * 16 + cq * 4 + rr;
        float val = acc[i][j][rr] + bv;
        if (EPI == 0){
          outb[(size_t)row * N + col] = f2bf(val);
        } else if (EPI == 2){
          float gg = 0.5f * val * (1.f + erff(val * 0.70710678118f));
          outb[(size_t)row * N + col] = f2bf(gg);
        } else if (EPI == 1){
          int win = row >> 6, n = row & 63;
          int b = win >> 6, wh = (win >> 3) & 7, ww = win & 7;
          int h = (wh * 8 + (n >> 3) + shift) & 63;
          int w = (ww * 8 + (n & 7) + shift) & 63;
          X[((size_t)(b << 12) + h * 64 + w) * 256 + col] += val;
        } else if (EPI == 3){
          X[(size_t)row * 256 + col] += val;
        } else {
          outf[(size_t)row * 256 + col] = X[(size_t)row * 256 + col] + val;
        }
      }
    }
  }
}

// ---------------- MFMA window attention: block = window, wave = head ----------------
// LDS strides (u16), all %8==0 for 16B-aligned ds_read_b128, padded so a 16-lane
// b128 read touches each bank <=2x (free per m136):
#define KS 40   // K stage: [head][tok 64][KS]   (40960 B)
#define VS 72   // V^T     : [head][d 32][VS]    (36864 B, reuses K buffer)
#define PS 72   // P scratch per wave: [16][PS]  (8 waves -> 18432 B)
__global__ __launch_bounds__(512, 2) void attn_mfma(
    const u16* __restrict__ qkv, const float* __restrict__ rpb,
    u16* __restrict__ out, int shifted)
{
  __shared__ __align__(16) u16 kv_s[8 * 64 * KS];   // K phase; reused as V^T (8*32*VS <= this)
  __shared__ __align__(16) u16 ps[8 * 16 * PS];
  __shared__ float rpb_s[225 * 8];
  int tid = threadIdx.x;
  int win = blockIdx.x;
  int wv = tid >> 6;               // wave index = head
  int lane = tid & 63;
  int g = lane >> 4, c = lane & 15;
  const u16* base = qkv + (size_t)win * 64 * 768;

  for (int i = tid; i < 1800; i += 512) rpb_s[i] = rpb[i];
  // stage K: kv_s[h][tok][d]  (lanes: dg minor, tok next -> conflict-free-ish writes)
  for (int cc = tid; cc < 2048; cc += 512){
    int dg = cc & 3, tok = (cc >> 2) & 63, hh = cc >> 8;
    u16x8 u = *(const u16x8*)&base[tok * 768 + 256 + hh * 32 + dg * 8];
    *(u16x8*)&kv_s[hh * 64 * KS + tok * KS + dg * 8] = u;
  }
  __syncthreads();

  int h = wv;
  // S = (Q*scale) K^T via 16 mfma (K-dim = 32 = one step)
  bf16x8 qa[4], kb[4];
  #pragma unroll
  for (int i = 0; i < 4; i++)
    qa[i] = *(const bf16x8*)&base[(i * 16 + c) * 768 + h * 32 + g * 8];
  #pragma unroll
  for (int j = 0; j < 4; j++)
    kb[j] = *(const bf16x8*)&kv_s[h * 64 * KS + (j * 16 + c) * KS + g * 8];
  f32x4 sacc[4][4];
  #pragma unroll
  for (int i = 0; i < 4; i++)
    #pragma unroll
    for (int j = 0; j < 4; j++)
      #pragma unroll
      for (int r = 0; r < 4; r++) sacc[i][j][r] = 0.f;
  #pragma unroll
  for (int i = 0; i < 4; i++)
    #pragma unroll
    for (int j = 0; j < 4; j++)
      sacc[i][j] = __builtin_amdgcn_mfma_f32_16x16x32_bf16(qa[i], kb[j], sacc[i][j], 0, 0, 0);

  // scale + rel-pos bias + mask + softmax (rows spread over 16-lane groups)
  int wh = (win >> 3) & 7, ww = win & 7;
  int mH[4], mW[4], idm[4];
  #pragma unroll
  for (int j = 0; j < 4; j++){
    int m = j * 16 + c;
    mH[j] = m >> 3; mW[j] = m & 7;
    idm[j] = 3 * regid(wh * 8 + mH[j]) + regid(ww * 8 + mW[j]);
  }
  unsigned pp[4][4][2];   // P premultiplied by 1/rowsum, packed bf16 pairs (r0r1, r2r3)
  #pragma unroll
  for (int i = 0; i < 4; i++){
    float ex[4][4];       // [j][r]
    float mx[4] = {-1e30f, -1e30f, -1e30f, -1e30f};
    #pragma unroll
    for (int r = 0; r < 4; r++){
      int n = i * 16 + g * 4 + r;
      int nh = n >> 3, nw = n & 7;
      int idn = 3 * regid(wh * 8 + nh) + regid(ww * 8 + nw);
      #pragma unroll
      for (int j = 0; j < 4; j++){
        float v = sacc[i][j][r] * SCALE
                + rpb_s[((nh - mH[j] + 7) * 15 + (nw - mW[j] + 7)) * 8 + h];
        if (shifted && idm[j] != idn) v -= 100.f;
        ex[j][r] = v;
        mx[r] = fmaxf(mx[r], v);
      }
    }
    #pragma unroll
    for (int r = 0; r < 4; r++){
      #pragma unroll
      for (int msk = 1; msk < 16; msk <<= 1) mx[r] = fmaxf(mx[r], __shfl_xor(mx[r], msk));
    }
    float sm[4] = {0.f, 0.f, 0.f, 0.f};
    #pragma unroll
    for (int j = 0; j < 4; j++)
      #pragma unroll
      for (int r = 0; r < 4; r++){ ex[j][r] = __expf(ex[j][r] - mx[r]); sm[r] += ex[j][r]; }
    #pragma unroll
    for (int r = 0; r < 4; r++){
      #pragma unroll
      for (int msk = 1; msk < 16; msk <<= 1) sm[r] += __shfl_xor(sm[r], msk);
      sm[r] = 1.f / sm[r];
    }
    #pragma unroll
    for (int j = 0; j < 4; j++){
      pp[i][j][0] = ((unsigned)f2bf(ex[j][1] * sm[1]) << 16) | f2bf(ex[j][0] * sm[0]);
      pp[i][j][1] = ((unsigned)f2bf(ex[j][3] * sm[3]) << 16) | f2bf(ex[j][2] * sm[2]);
    }
  }

  __syncthreads();   // all waves done reading K from kv_s
  // stage V^T: kv_s[h][d][tok]  (lanes: tok minor -> conflict-free scalar writes)
  for (int cc = tid; cc < 2048; cc += 512){
    int tok = cc & 63, dg = (cc >> 6) & 3, hh = cc >> 8;
    u16x8 u = *(const u16x8*)&base[tok * 768 + 512 + hh * 32 + dg * 8];
    #pragma unroll
    for (int j = 0; j < 8; j++)
      kv_s[hh * 32 * VS + (dg * 8 + j) * VS + tok] = u[j];
  }
  __syncthreads();

  // O = P V via 16 mfma (K-dim 64 = 2 steps, 2 d-tiles)
  bf16x8 vb[2][2];
  #pragma unroll
  for (int k4 = 0; k4 < 2; k4++)
    #pragma unroll
    for (int t = 0; t < 2; t++)
      vb[k4][t] = *(const bf16x8*)&kv_s[h * 32 * VS + (t * 16 + c) * VS + k4 * 32 + g * 8];

  u16* pw = &ps[wv * 16 * PS];
  f32x4 oacc[4][2];
  #pragma unroll
  for (int i = 0; i < 4; i++)
    #pragma unroll
    for (int t = 0; t < 2; t++)
      #pragma unroll
      for (int r = 0; r < 4; r++) oacc[i][t][r] = 0.f;

  #pragma unroll
  for (int i = 0; i < 4; i++){
    // write P tile (C-layout) to per-wave LDS scratch
    #pragma unroll
    for (int j = 0; j < 4; j++)
      #pragma unroll
      for (int r = 0; r < 4; r++)
        pw[(g * 4 + r) * PS + j * 16 + c] = (u16)(pp[i][j][r >> 1] >> ((r & 1) * 16));
    // read back in A-layout (DS ops are wave-ordered; compiler inserts lgkm waits)
    bf16x8 pa0 = *(const bf16x8*)&pw[c * PS + 0  + g * 8];
    bf16x8 pa1 = *(const bf16x8*)&pw[c * PS + 32 + g * 8];
    #pragma unroll
    for (int t = 0; t < 2; t++){
      oacc[i][t] = __builtin_amdgcn_mfma_f32_16x16x32_bf16(pa0, vb[0][t], oacc[i][t], 0, 0, 0);
      oacc[i][t] = __builtin_amdgcn_mfma_f32_16x16x32_bf16(pa1, vb[1][t], oacc[i][t], 0, 0, 0);
    }
  }

  u16* op = out + (size_t)(win * 64) * 256 + h * 32;
  #pragma unroll
  for (int i = 0; i < 4; i++)
    #pragma unroll
    for (int t = 0; t < 2; t++)
      #pragma unroll
      for (int r = 0; r < 4; r++)
        op[(size_t)(i * 16 + g * 4 + r) * 256 + t * 16 + c] = f2bf(oacc[i][t][r]);
}

// ---------------- launch ----------------
extern "C" void kernel_launch(void* const* d_in, const int* in_sizes, int n_in,
                              void* d_out, int out_size, void* d_ws, size_t ws_size,
                              hipStream_t stream)
{
  const float* x = (const float*)d_in[0];
  const float* p[2][13];
  for (int blk = 0; blk < 2; blk++)
    for (int i = 0; i < 13; i++) p[blk][i] = (const float*)d_in[1 + blk * 13 + i];
  // 0 n1g 1 n1b 2 qkvw 3 qkvb 4 rpb 5 pw 6 pb 7 n2g 8 n2b 9 f1w 10 f1b 11 f2w 12 f2b

  char* ws = (char*)d_ws;
  float* X  = (float*)ws;                            // 64 MB fp32 residual
  u16* HW   = (u16*)(ws + ((size_t)64 << 20));       // 32 MB (LN out / attn out)
  u16* BIG  = (u16*)(ws + ((size_t)96 << 20));       // 128 MB (QKV / MLP hidden)
  u16* WT   = (u16*)(ws + ((size_t)224 << 20));      // 3 MB transposed bf16 weights

  cvt_copy<<<ROWS * 256 / (256 * 8), 256, 0, stream>>>(x, X);
  transpose_all<<<dim3(32, 32, 8), 256, 0, stream>>>(
      p[0][2], p[0][5], p[0][9], p[0][11], p[1][2], p[1][5], p[1][9], p[1][11], WT);

  for (int blk = 0; blk < 2; blk++){
    int shift = blk ? 4 : 0;
    const u16* qkvw_t = WT + (size_t)blk * 786432;
    const u16* pw_t   = WT + (size_t)blk * 786432 + 196608;
    const u16* f1w_t  = WT + (size_t)blk * 786432 + 262144;
    const u16* f2w_t  = WT + (size_t)blk * 786432 + 524288;

    ln_kernel<<<ROWS / 4, 256, 0, stream>>>(X, p[blk][0], p[blk][1], HW, 1, shift);
    gemm_bt<0><<<dim3(6, 512), 256, 0, stream>>>(HW, qkvw_t, p[blk][3], BIG, nullptr, X, 768, 256, 0);
    attn_mfma<<<NWT, 512, 0, stream>>>(BIG, p[blk][4], HW, blk);
    gemm_bt<1><<<dim3(2, 512), 256, 0, stream>>>(HW, pw_t, p[blk][6], nullptr, nullptr, X, 256, 256, shift);
    ln_kernel<<<ROWS / 4, 256, 0, stream>>>(X, p[blk][7], p[blk][8], HW, 0, 0);
    gemm_bt<2><<<dim3(8, 512), 256, 0, stream>>>(HW, f1w_t, p[blk][10], BIG, nullptr, X, 1024, 256, 0);
    if (blk == 0)
      gemm_bt<3><<<dim3(2, 512), 256, 0, stream>>>(BIG, f2w_t, p[blk][12], nullptr, nullptr, X, 256, 1024, 0);
    else
      gemm_bt<4><<<dim3(2, 512), 256, 0, stream>>>(BIG, f2w_t, p[blk][12], nullptr, (float*)d_out, X, 256, 1024, 0);
  }
}